// Round 8
// baseline (271.749 us; speedup 1.0000x reference)
//
#include <hip/hip_runtime.h>

#define NN 50000
#define NE 800000
#define D 128

#define CH 64              // edge chunks
#define EPC (NE / CH)      // 12500 edges per chunk
#define RGH 2              // node ranges (packed 16-bit counts: 100KB LDS)
#define NPR2 (NN / RGH)    // 25000 nodes per range
#define CSRCAP (NE + 4 * NN)

#define HIST_BLOCKS (CH * RGH)  // 128
#define CVT_BLOCKS 1563         // ceil(1.6M / 1024)
#define WT_BLOCKS 48            // 3 matrices x 16384 / 1024

typedef short bf16x8 __attribute__((ext_vector_type(8)));
typedef float f32x4 __attribute__((ext_vector_type(4)));

// ---------------- bf16 helpers ----------------

__device__ __forceinline__ unsigned bf16rne(float f) {
  unsigned u = __float_as_uint(f);
  return (u + 0x7fffu + ((u >> 16) & 1u)) >> 16;
}
__device__ __forceinline__ unsigned packbf(float lo, float hi) {
  return bf16rne(lo) | (bf16rne(hi) << 16);
}
__device__ __forceinline__ void bacc(float* a, uint4 u) {
  a[0] += __uint_as_float(u.x << 16);
  a[1] += __uint_as_float(u.x & 0xffff0000u);
  a[2] += __uint_as_float(u.y << 16);
  a[3] += __uint_as_float(u.y & 0xffff0000u);
  a[4] += __uint_as_float(u.z << 16);
  a[5] += __uint_as_float(u.z & 0xffff0000u);
  a[6] += __uint_as_float(u.w << 16);
  a[7] += __uint_as_float(u.w & 0xffff0000u);
}

// fused: packed hist (blocks 0..127) | x->bf16 | W^T bf16 x3 | zero row NN
// hist: one LDS uint per node packs dst-count (lo16) and src-count (hi16);
// max degree ~50 so no overflow. CH=64 x RGH=2 -> 128 blocks, partial
// traffic 12.8MB (r7's CH=128 doubled it -- reverted).
__global__ __launch_bounds__(1024) void prep_kernel(
    const float* __restrict__ x, const float* __restrict__ W1,
    const float* __restrict__ W2, const float* __restrict__ W3,
    unsigned short* __restrict__ hbf, unsigned short* __restrict__ T1,
    unsigned short* __restrict__ T2, unsigned short* __restrict__ T3,
    const int* __restrict__ src, const int* __restrict__ dst,
    unsigned* __restrict__ partial) {
  __shared__ unsigned hcnt[NPR2];  // 100KB
  int b = blockIdx.x;
  int tid = threadIdx.x;
  if (b < HIST_BLOCKS) {
    int c = b >> 1;
    int r = b & 1;
    int base = r * NPR2;
    for (int i = tid; i < NPR2; i += 1024) hcnt[i] = 0;
    __syncthreads();
    int e0 = c * EPC;
    for (int i = tid; i < EPC; i += 1024) {
      int d = dst[e0 + i];
      int s = src[e0 + i];
      unsigned dr = (unsigned)(d - base);
      unsigned sr = (unsigned)(s - base);
      if (dr < NPR2) atomicAdd(&hcnt[dr], 1u);
      if (sr < NPR2) atomicAdd(&hcnt[sr], 0x10000u);
    }
    __syncthreads();
    for (int i = tid; i < NPR2; i += 1024)
      partial[(size_t)c * NN + base + i] = hcnt[i];
  } else if (b < HIST_BLOCKS + CVT_BLOCKS) {
    int i = (b - HIST_BLOCKS) * 1024 + tid;
    if (i < NN * D / 4) {
      float4 v = ((const float4*)x)[i];
      uint2 p;
      p.x = packbf(v.x, v.y);
      p.y = packbf(v.z, v.w);
      ((uint2*)hbf)[i] = p;
    }
  } else if (b < HIST_BLOCKS + CVT_BLOCKS + WT_BLOCKS) {
    int g = b - (HIST_BLOCKS + CVT_BLOCKS);
    int w = g >> 4;
    int i = (g & 15) * 1024 + tid;  // 0..16383
    const float* W = (w == 0) ? W1 : (w == 1) ? W2 : W3;
    unsigned short* T = (w == 0) ? T1 : (w == 1) ? T2 : T3;
    int n = i >> 7, k = i & 127;
    T[n * 128 + k] = (unsigned short)bf16rne(W[k * 128 + n]);
  } else {
    if (tid < 16) ((uint4*)(hbf + (size_t)NN * D))[tid] = make_uint4(0, 0, 0, 0);
  }
}

// ---------------- parallel degscan: 16 threads per node ---------------------
// Replaces the serial 196-block chunk loop (r3/r7's main build bottleneck:
// <1 block/CU, 32-128 dependent strided loads per thread). 3125 blocks;
// thread (node_i, tc) owns 4 chunks; width-16 shfl scan gives per-chunk
// exclusive offsets -> pofs (u16; prefix <= deg <= ~50). Lane 15 writes
// deg_in (degtmp) and deg_out.
__global__ __launch_bounds__(256) void pdegscan_kernel(const unsigned* __restrict__ partial,
                                                       unsigned short* __restrict__ pofs,
                                                       int* __restrict__ degtmp,
                                                       int* __restrict__ deg_out) {
  int tid = threadIdx.x;
  int node_i = tid >> 4;
  int tc = tid & 15;
  int d = blockIdx.x * 16 + node_i;  // 3125*16 == NN exactly
  int c0 = tc * 4;
  unsigned v0 = partial[(size_t)(c0 + 0) * NN + d];
  unsigned v1 = partial[(size_t)(c0 + 1) * NN + d];
  unsigned v2 = partial[(size_t)(c0 + 2) * NN + d];
  unsigned v3 = partial[(size_t)(c0 + 3) * NN + d];
  int d0 = (int)(v0 & 0xffffu), d1 = (int)(v1 & 0xffffu);
  int d2 = (int)(v2 & 0xffffu), d3 = (int)(v3 & 0xffffu);
  int tsum = d0 + d1 + d2 + d3;
  int ssum = (int)(v0 >> 16) + (int)(v1 >> 16) + (int)(v2 >> 16) + (int)(v3 >> 16);
  int incl = tsum, incs = ssum;
#pragma unroll
  for (int off = 1; off < 16; off <<= 1) {
    int t0 = __shfl_up(incl, off, 16);
    int t1 = __shfl_up(incs, off, 16);
    if (tc >= off) { incl += t0; incs += t1; }
  }
  int excl = incl - tsum;
  pofs[(size_t)(c0 + 0) * NN + d] = (unsigned short)excl;
  pofs[(size_t)(c0 + 1) * NN + d] = (unsigned short)(excl + d0);
  pofs[(size_t)(c0 + 2) * NN + d] = (unsigned short)(excl + d0 + d1);
  pofs[(size_t)(c0 + 3) * NN + d] = (unsigned short)(excl + d0 + d1 + d2);
  if (tc == 15) {
    degtmp[d] = incl;
    deg_out[d] = incs;
  }
}

__device__ __forceinline__ int block_excl_scan(int v, int* wsum) {
  int lane = threadIdx.x & 63;
  int w = threadIdx.x >> 6;
  int incl = v;
#pragma unroll
  for (int off = 1; off < 64; off <<= 1) {
    int t = __shfl_up(incl, off);
    if (lane >= off) incl += t;
  }
  if (lane == 63) wsum[w] = incl;
  __syncthreads();
  int wo = 0;
#pragma unroll
  for (int j = 0; j < 4; ++j)
    if (j < w) wo += wsum[j];
  return wo + incl - v;
}

// block-LOCAL exclusive scan of PADDED (ceil4) degree -> row_ptr, block
// totals -> partials. Consumers add partials[node>>8].
__global__ __launch_bounds__(256) void rowscan_kernel(const int* __restrict__ degtmp,
                                                      int* __restrict__ row_ptr,
                                                      int* __restrict__ partials, int N) {
  __shared__ int wsum[4];
  int d = blockIdx.x * 256 + threadIdx.x;
  int run = (d < N) ? degtmp[d] : 0;
  int pad = (run + 3) & ~3;
  int excl = block_excl_scan(pad, wsum);
  if (d <= N) row_ptr[d] = excl;
  if (threadIdx.x == 255) partials[blockIdx.x] = excl + pad;
}

__global__ __launch_bounds__(256) void scan2(int* __restrict__ partials, int nb) {
  __shared__ int wsum[4];
  int v = (threadIdx.x < nb) ? partials[threadIdx.x] : 0;
  int excl = block_excl_scan(v, wsum);
  if (threadIdx.x < nb) partials[threadIdx.x] = excl;
}

// scatter fill, 128 blocks (CH=64 x RGH=2); the last-chunk blocks also write
// the NN-dummy pad tails (cur[] ends at row start + deg exactly; pad slots
// are disjoint from data slots, no inter-block ordering needed).
__global__ __launch_bounds__(1024) void fill_kernel(const int* __restrict__ src,
                                                    const int* __restrict__ dst,
                                                    const int* __restrict__ row_ptr,
                                                    const int* __restrict__ partials,
                                                    const unsigned short* __restrict__ pofs,
                                                    int* __restrict__ csr_src) {
  __shared__ int cur[NPR2];  // 100KB
  int tid = threadIdx.x;
  int c = blockIdx.x >> 1;
  int r = blockIdx.x & 1;
  int base = r * NPR2;
  for (int i = tid; i < NPR2; i += 1024) {
    int nd = base + i;
    cur[i] = row_ptr[nd] + partials[nd >> 8] + (int)pofs[(size_t)c * NN + nd];
  }
  __syncthreads();
  int e0 = c * EPC;
  for (int i = tid; i < EPC; i += 1024) {
    int d = dst[e0 + i];
    unsigned dr = (unsigned)(d - base);
    if (dr < NPR2) {
      int pos = atomicAdd(&cur[dr], 1);
      csr_src[pos] = src[e0 + i];
    }
  }
  if (c == CH - 1) {
    __syncthreads();
    for (int i = tid; i < NPR2; i += 1024) {
      int nd = base + i;
      int s = cur[i];  // == global row start + deg
      int e = row_ptr[nd + 1] + partials[(nd + 1) >> 8];
      for (int j = s; j < e; ++j) csr_src[j] = NN;
    }
  }
}

// ---------------- aggregation: one QUARTER-WAVE (16 lanes) per node ---------
// (round-3 proven version, unchanged) Each lane owns 8 channels of one node;
// edges consumed 4 at a time via one int4 index load. Rows padded to x4 with
// dummy index NN (zero row). MODE 0: sage. MODE 1: gcn rsqrt.
template <int MODE>
__global__ __launch_bounds__(256, 8) void agg_kernel(const unsigned short* __restrict__ hb,
                                                     const int* __restrict__ row_ptr,
                                                     const int* __restrict__ partials,
                                                     const int* __restrict__ csr_src,
                                                     const int* __restrict__ degtmp,
                                                     unsigned short* __restrict__ outb, int N) {
  int qw = threadIdx.x >> 4;   // 0..15: quarter-wave = node slot
  int col = threadIdx.x & 15;  // 16B granule within row
  int node = blockIdx.x * 16 + qw;
  if (node >= N) return;
  int start = row_ptr[node] + partials[node >> 8];
  int end = row_ptr[node + 1] + partials[(node + 1) >> 8];
  int indeg = degtmp[node];
  uint4 srow = make_uint4(0, 0, 0, 0);
  if (MODE == 0) srow = ((const uint4*)(hb + (size_t)node * D))[col];
  float a0[8] = {0, 0, 0, 0, 0, 0, 0, 0};
  float a1[8] = {0, 0, 0, 0, 0, 0, 0, 0};
  const int* ce = csr_src + start;
  int cnt = end - start;  // multiple of 4
  for (int it = 0; it < cnt; it += 4) {
    int4 ix = *(const int4*)(ce + it);
    uint4 u0 = ((const uint4*)(hb + (size_t)ix.x * D))[col];
    uint4 u1 = ((const uint4*)(hb + (size_t)ix.y * D))[col];
    uint4 u2 = ((const uint4*)(hb + (size_t)ix.z * D))[col];
    uint4 u3 = ((const uint4*)(hb + (size_t)ix.w * D))[col];
    bacc(a0, u0);
    bacc(a1, u1);
    bacc(a0, u2);
    bacc(a1, u3);
  }
#pragma unroll
  for (int j = 0; j < 8; ++j) a0[j] += a1[j];
  if (MODE == 0) {
    float sf[8] = {0, 0, 0, 0, 0, 0, 0, 0};
    bacc(sf, srow);
    float inv = 1.0f / (float)(indeg + 1);
#pragma unroll
    for (int j = 0; j < 8; ++j) a0[j] = (a0[j] + sf[j]) * inv;
  } else {
    float sc = rsqrtf(fmaxf((float)indeg, 1.0f));
#pragma unroll
    for (int j = 0; j < 8; ++j) a0[j] *= sc;
  }
  uint4 p;
  p.x = packbf(a0[0], a0[1]);
  p.y = packbf(a0[2], a0[3]);
  p.z = packbf(a0[4], a0[5]);
  p.w = packbf(a0[6], a0[7]);
  ((uint4*)(outb + (size_t)node * D))[col] = p;
}

// ---------------- MFMA GEMM: [N x 128](bf16) @ [128 x 128] + bias ------------
// (round-3 proven version, unchanged)
template <int MODE, int OUT_BF>
__global__ __launch_bounds__(256) void mgemm_kernel(const unsigned short* __restrict__ A,
                                                    const unsigned short* __restrict__ WT,
                                                    const float* __restrict__ bias,
                                                    const int* __restrict__ deg_out,
                                                    float* __restrict__ outf,
                                                    unsigned short* __restrict__ outb, int N) {
  __shared__ unsigned short sWT[128 * 136];
  int tid = threadIdx.x;
  for (int g = tid; g < 2048; g += 256) {
    int n = g >> 4, c = g & 15;
    uint4 v = ((const uint4*)WT)[g];
    *(uint4*)&sWT[n * 136 + c * 8] = v;
  }
  int wv = tid >> 6;
  int lane = tid & 63;
  int q = lane >> 4;
  int ln = lane & 15;
  int row0 = blockIdx.x * 64 + wv * 16;
  int arow = row0 + ln;
  if (arow >= N) arow = 0;  // clamp; stores are guarded
  const unsigned short* Ar = A + (size_t)arow * 128 + q * 8;
  bf16x8 af0 = *(const bf16x8*)(Ar + 0);
  bf16x8 af1 = *(const bf16x8*)(Ar + 32);
  bf16x8 af2 = *(const bf16x8*)(Ar + 64);
  bf16x8 af3 = *(const bf16x8*)(Ar + 96);
  f32x4 acc[8];
#pragma unroll
  for (int t = 0; t < 8; ++t) acc[t] = (f32x4){0.f, 0.f, 0.f, 0.f};
  __syncthreads();
#pragma unroll
  for (int t = 0; t < 8; ++t) {
    const unsigned short* Wr = &sWT[(t * 16 + ln) * 136 + q * 8];
    bf16x8 b0 = *(const bf16x8*)(Wr + 0);
    bf16x8 b1 = *(const bf16x8*)(Wr + 32);
    bf16x8 b2 = *(const bf16x8*)(Wr + 64);
    bf16x8 b3 = *(const bf16x8*)(Wr + 96);
    acc[t] = __builtin_amdgcn_mfma_f32_16x16x32_bf16(af0, b0, acc[t], 0, 0, 0);
    acc[t] = __builtin_amdgcn_mfma_f32_16x16x32_bf16(af1, b1, acc[t], 0, 0, 0);
    acc[t] = __builtin_amdgcn_mfma_f32_16x16x32_bf16(af2, b2, acc[t], 0, 0, 0);
    acc[t] = __builtin_amdgcn_mfma_f32_16x16x32_bf16(af3, b3, acc[t], 0, 0, 0);
  }
  float scl[4];
#pragma unroll
  for (int r = 0; r < 4; ++r) {
    scl[r] = 1.0f;
    if (MODE == 1) {
      int row = row0 + q * 4 + r;
      int rr = (row < N) ? row : 0;
      scl[r] = rsqrtf(fmaxf((float)deg_out[rr], 1.0f));
    }
  }
#pragma unroll
  for (int t = 0; t < 8; ++t) {
    float b = bias[t * 16 + ln];
#pragma unroll
    for (int r = 0; r < 4; ++r) {
      int row = row0 + q * 4 + r;
      if (row < N) {
        float v = (acc[t][r] + b) * scl[r];
        if (OUT_BF)
          outb[(size_t)row * 128 + t * 16 + ln] = (unsigned short)bf16rne(v);
        else
          outf[(size_t)row * 128 + t * 16 + ln] = v;
      }
    }
  }
}

// ---------------- launcher ----------------

extern "C" void kernel_launch(void* const* d_in, const int* in_sizes, int n_in,
                              void* d_out, int out_size, void* d_ws, size_t ws_size,
                              hipStream_t stream) {
  const float* x = (const float*)d_in[0];
  const float* W1 = (const float*)d_in[1];
  const float* b1 = (const float*)d_in[2];
  const float* W2 = (const float*)d_in[3];
  const float* b2 = (const float*)d_in[4];
  const float* W3 = (const float*)d_in[5];
  const float* b3 = (const float*)d_in[6];
  const int* src = (const int*)d_in[7];
  const int* dst = (const int*)d_in[8];
  float* out = (float*)d_out;

  const int N = NN;

  // workspace layout (~37 MB). aggB aliases the (dead-after-pdegscan)
  // partial array; pofs stays live through fill.
  unsigned short* hbf = (unsigned short*)d_ws;         // (NN+1)*D bf16
  unsigned short* WT1 = hbf + (size_t)(NN + 1) * D;    // 128*128 bf16 x3
  unsigned short* WT2 = WT1 + D * D;
  unsigned short* WT3 = WT2 + D * D;
  int* degtmp = (int*)(WT3 + D * D);                   // NN
  int* deg_out = degtmp + NN;                          // NN
  int* row_ptr = deg_out + NN;                         // NN+1 (alloc NN+4)
  int* partials = row_ptr + NN + 4;                    // 256
  int* csr_src = partials + 256;                       // CSRCAP
  unsigned* partial = (unsigned*)(csr_src + CSRCAP);   // CH*NN uint (12.8MB)
  unsigned short* pofs = (unsigned short*)(partial + (size_t)CH * NN);  // CH*NN u16
  unsigned short* aggB = (unsigned short*)partial;     // NN*D bf16 (aliases partial)

  const int scanBlocks = (N + 255) / 256;  // 196

  prep_kernel<<<HIST_BLOCKS + CVT_BLOCKS + WT_BLOCKS + 1, 1024, 0, stream>>>(
      x, W1, W2, W3, hbf, WT1, WT2, WT3, src, dst, partial);
  pdegscan_kernel<<<NN / 16, 256, 0, stream>>>(partial, pofs, degtmp, deg_out);
  rowscan_kernel<<<scanBlocks, 256, 0, stream>>>(degtmp, row_ptr, partials, N);
  scan2<<<1, 256, 0, stream>>>(partials, scanBlocks);
  fill_kernel<<<HIST_BLOCKS, 1024, 0, stream>>>(src, dst, row_ptr, partials, pofs,
                                                csr_src);

  int aggBlocks = (N + 15) / 16;  // 3125
  int gemmBlocks = (N + 63) / 64;

  // layer 1: sage(x)
  agg_kernel<0><<<aggBlocks, 256, 0, stream>>>(hbf, row_ptr, partials, csr_src, degtmp,
                                               aggB, N);
  mgemm_kernel<0, 1><<<gemmBlocks, 256, 0, stream>>>(aggB, WT1, b1, deg_out, nullptr, hbf, N);
  // layer 2: sage(h1); fold norm_out for layer 3 into epilogue
  agg_kernel<0><<<aggBlocks, 256, 0, stream>>>(hbf, row_ptr, partials, csr_src, degtmp,
                                               aggB, N);
  mgemm_kernel<1, 1><<<gemmBlocks, 256, 0, stream>>>(aggB, WT2, b2, deg_out, nullptr, hbf, N);
  // layer 3: gcn: (agg(h2*norm_out) * norm_in) @ W3 + b3
  agg_kernel<1><<<aggBlocks, 256, 0, stream>>>(hbf, row_ptr, partials, csr_src, degtmp,
                                               aggB, N);
  mgemm_kernel<0, 0><<<gemmBlocks, 256, 0, stream>>>(aggB, WT3, b3, deg_out, out, nullptr, N);
}

// Round 9
// 260.069 us; speedup vs baseline: 1.0449x; 1.0449x over previous
//
#include <hip/hip_runtime.h>

#define NN 50000
#define NE 800000
#define D 128

#define CH 32              // edge chunks
#define EPC (NE / CH)      // 25000 edges per chunk
#define RGH 4              // node ranges (160KB LDS lets us halve the passes)
#define NPRH (NN / RGH)    // 12500 nodes per range
#define CSRCAP (NE + 4 * NN)

#define HIST_BLOCKS (CH * RGH)  // 128
#define CVT_BLOCKS 1563         // ceil(1.6M / 1024)
#define WT_BLOCKS 48            // 3 matrices x 16384 / 1024

typedef short bf16x8 __attribute__((ext_vector_type(8)));
typedef float f32x4 __attribute__((ext_vector_type(4)));

// ---------------- bf16 helpers ----------------

__device__ __forceinline__ unsigned bf16rne(float f) {
  unsigned u = __float_as_uint(f);
  return (u + 0x7fffu + ((u >> 16) & 1u)) >> 16;
}
__device__ __forceinline__ unsigned packbf(float lo, float hi) {
  return bf16rne(lo) | (bf16rne(hi) << 16);
}

// fused: hist (blocks 0..127) | x->bf16 | W^T bf16 x3 | zero row NN
__global__ __launch_bounds__(1024) void cvtw_hist_kernel(
    const float* __restrict__ x, const float* __restrict__ W1,
    const float* __restrict__ W2, const float* __restrict__ W3,
    unsigned short* __restrict__ hbf, unsigned short* __restrict__ T1,
    unsigned short* __restrict__ T2, unsigned short* __restrict__ T3,
    const int* __restrict__ src, const int* __restrict__ dst,
    int* __restrict__ partial_dst, int* __restrict__ partial_src) {
  __shared__ int hd[NPRH];
  __shared__ int hs[NPRH];
  int b = blockIdx.x;
  int tid = threadIdx.x;
  if (b < HIST_BLOCKS) {
    int c = b >> 2;
    int r = b & 3;
    int base = r * NPRH;
    for (int i = tid; i < NPRH; i += 1024) { hd[i] = 0; hs[i] = 0; }
    __syncthreads();
    int e0 = c * EPC;
    for (int i = tid; i < EPC; i += 1024) {
      int d = dst[e0 + i];
      int s = src[e0 + i];
      unsigned dr = (unsigned)(d - base);
      unsigned sr = (unsigned)(s - base);
      if (dr < NPRH) atomicAdd(&hd[dr], 1);
      if (sr < NPRH) atomicAdd(&hs[sr], 1);
    }
    __syncthreads();
    for (int i = tid; i < NPRH; i += 1024) {
      partial_dst[c * NN + base + i] = hd[i];
      partial_src[c * NN + base + i] = hs[i];
    }
  } else if (b < HIST_BLOCKS + CVT_BLOCKS) {
    int i = (b - HIST_BLOCKS) * 1024 + tid;
    if (i < NN * D / 4) {
      float4 v = ((const float4*)x)[i];
      uint2 p;
      p.x = packbf(v.x, v.y);
      p.y = packbf(v.z, v.w);
      ((uint2*)hbf)[i] = p;
    }
  } else if (b < HIST_BLOCKS + CVT_BLOCKS + WT_BLOCKS) {
    int g = b - (HIST_BLOCKS + CVT_BLOCKS);
    int w = g >> 4;
    int i = (g & 15) * 1024 + tid;  // 0..16383
    const float* W = (w == 0) ? W1 : (w == 1) ? W2 : W3;
    unsigned short* T = (w == 0) ? T1 : (w == 1) ? T2 : T3;
    int n = i >> 7, k = i & 127;
    T[n * 128 + k] = (unsigned short)bf16rne(W[k * 128 + n]);
  } else {
    if (tid < 16) ((uint4*)(hbf + (size_t)NN * D))[tid] = make_uint4(0, 0, 0, 0);
  }
}

__device__ __forceinline__ int block_excl_scan(int v, int* wsum) {
  int lane = threadIdx.x & 63;
  int w = threadIdx.x >> 6;
  int incl = v;
#pragma unroll
  for (int off = 1; off < 64; off <<= 1) {
    int t = __shfl_up(incl, off);
    if (lane >= off) incl += t;
  }
  if (lane == 63) wsum[w] = incl;
  __syncthreads();
  int wo = 0;
#pragma unroll
  for (int j = 0; j < 4; ++j)
    if (j < w) wo += wsum[j];
  return wo + incl - v;
}

// fused reduce + scan phase 1: chunk-prefix partial_dst in place, true in-deg
// -> degtmp, out-deg -> deg_out, block-LOCAL exclusive scan of PADDED degree
// (ceil4) -> row_ptr, block totals -> partials. Consumers add partials[n>>8];
// no scan3 pass needed.
__global__ __launch_bounds__(256) void degscan_kernel(int* __restrict__ partial_dst,
                                                      const int* __restrict__ partial_src,
                                                      int* __restrict__ degtmp,
                                                      int* __restrict__ deg_out,
                                                      int* __restrict__ row_ptr,
                                                      int* __restrict__ partials, int N) {
  __shared__ int wsum[4];
  int d = blockIdx.x * 256 + threadIdx.x;
  int run = 0;
  if (d < N) {
#pragma unroll
    for (int c = 0; c < CH; ++c) {
      int v = partial_dst[c * NN + d];
      partial_dst[c * NN + d] = run;
      run += v;
    }
    degtmp[d] = run;
    int ro = 0;
#pragma unroll
    for (int c = 0; c < CH; ++c) ro += partial_src[c * NN + d];
    deg_out[d] = ro;
  }
  int pad = (run + 3) & ~3;
  int excl = block_excl_scan(pad, wsum);
  if (d <= N) row_ptr[d] = excl;  // d==N gets local end-of-block-195 prefix
  if (threadIdx.x == 255) partials[blockIdx.x] = excl + pad;
}

__global__ __launch_bounds__(256) void scan2(int* __restrict__ partials, int nb) {
  __shared__ int wsum[4];
  int v = (threadIdx.x < nb) ? partials[threadIdx.x] : 0;
  int excl = block_excl_scan(v, wsum);
  if (threadIdx.x < nb) partials[threadIdx.x] = excl;
}

// scatter fill; the last-chunk block also writes the NN-dummy pad tails
// (pad slots are disjoint from data slots, and this block's cur[] ends at
// row_start + deg exactly, so no inter-block ordering is needed).
__global__ __launch_bounds__(1024) void fill_kernel(const int* __restrict__ src,
                                                    const int* __restrict__ dst,
                                                    const int* __restrict__ row_ptr,
                                                    const int* __restrict__ partials,
                                                    const int* __restrict__ partial_dst,
                                                    int* __restrict__ csr_src) {
  __shared__ int cur[NPRH];
  int tid = threadIdx.x;
  int c = blockIdx.x >> 2;
  int r = blockIdx.x & 3;
  int base = r * NPRH;
  for (int i = tid; i < NPRH; i += 1024) {
    int nd = base + i;
    cur[i] = row_ptr[nd] + partials[nd >> 8] + partial_dst[c * NN + nd];
  }
  __syncthreads();
  int e0 = c * EPC;
  for (int i = tid; i < EPC; i += 1024) {
    int d = dst[e0 + i];
    unsigned dr = (unsigned)(d - base);
    if (dr < NPRH) {
      int pos = atomicAdd(&cur[dr], 1);
      csr_src[pos] = src[e0 + i];
    }
  }
  if (c == CH - 1) {
    __syncthreads();
    for (int i = tid; i < NPRH; i += 1024) {
      int nd = base + i;
      int s = cur[i];  // == global row start + deg
      int e = row_ptr[nd + 1] + partials[(nd + 1) >> 8];
      for (int j = s; j < e; ++j) csr_src[j] = NN;
    }
  }
}

// ---------------- aggregation: one QUARTER-WAVE (16 lanes) per node ---------
// Each lane owns 8 channels of one node; edges consumed 4 at a time via one
// int4 index load -> 16 row-loads in flight per wave, zero cross-lane
// shuffles. Rows padded to x4 with dummy index NN (zero row).
// bf16 in, f32 accumulate, bf16 out. MODE 0: sage. MODE 1: gcn rsqrt.
__device__ __forceinline__ void bacc(float* a, uint4 u) {
  a[0] += __uint_as_float(u.x << 16);
  a[1] += __uint_as_float(u.x & 0xffff0000u);
  a[2] += __uint_as_float(u.y << 16);
  a[3] += __uint_as_float(u.y & 0xffff0000u);
  a[4] += __uint_as_float(u.z << 16);
  a[5] += __uint_as_float(u.z & 0xffff0000u);
  a[6] += __uint_as_float(u.w << 16);
  a[7] += __uint_as_float(u.w & 0xffff0000u);
}

template <int MODE>
__global__ __launch_bounds__(256, 8) void agg_kernel(const unsigned short* __restrict__ hb,
                                                     const int* __restrict__ row_ptr,
                                                     const int* __restrict__ partials,
                                                     const int* __restrict__ csr_src,
                                                     const int* __restrict__ degtmp,
                                                     unsigned short* __restrict__ outb, int N) {
  int qw = threadIdx.x >> 4;   // 0..15: quarter-wave = node slot
  int col = threadIdx.x & 15;  // 16B granule within row
  int node = blockIdx.x * 16 + qw;
  if (node >= N) return;
  int start = row_ptr[node] + partials[node >> 8];
  int end = row_ptr[node + 1] + partials[(node + 1) >> 8];
  int indeg = degtmp[node];
  uint4 srow = make_uint4(0, 0, 0, 0);
  if (MODE == 0) srow = ((const uint4*)(hb + (size_t)node * D))[col];
  float a0[8] = {0, 0, 0, 0, 0, 0, 0, 0};
  float a1[8] = {0, 0, 0, 0, 0, 0, 0, 0};
  const int* ce = csr_src + start;
  int cnt = end - start;  // multiple of 4
  for (int it = 0; it < cnt; it += 4) {
    int4 ix = *(const int4*)(ce + it);
    uint4 u0 = ((const uint4*)(hb + (size_t)ix.x * D))[col];
    uint4 u1 = ((const uint4*)(hb + (size_t)ix.y * D))[col];
    uint4 u2 = ((const uint4*)(hb + (size_t)ix.z * D))[col];
    uint4 u3 = ((const uint4*)(hb + (size_t)ix.w * D))[col];
    bacc(a0, u0);
    bacc(a1, u1);
    bacc(a0, u2);
    bacc(a1, u3);
  }
#pragma unroll
  for (int j = 0; j < 8; ++j) a0[j] += a1[j];
  if (MODE == 0) {
    float sf[8] = {0, 0, 0, 0, 0, 0, 0, 0};
    bacc(sf, srow);
    float inv = 1.0f / (float)(indeg + 1);
#pragma unroll
    for (int j = 0; j < 8; ++j) a0[j] = (a0[j] + sf[j]) * inv;
  } else {
    float sc = rsqrtf(fmaxf((float)indeg, 1.0f));
#pragma unroll
    for (int j = 0; j < 8; ++j) a0[j] *= sc;
  }
  uint4 p;
  p.x = packbf(a0[0], a0[1]);
  p.y = packbf(a0[2], a0[3]);
  p.z = packbf(a0[4], a0[5]);
  p.w = packbf(a0[6], a0[7]);
  ((uint4*)(outb + (size_t)node * D))[col] = p;
}

// ---------------- MFMA GEMM: [N x 128](bf16) @ [128 x 128] + bias ------------
// 256 thr = 4 waves; block tile 64 rows; wave tile 16 rows x 128 cols.
// MODE 1: scale rows by rsqrt(max(deg_out,1)). OUT_BF 1: write bf16 table.
template <int MODE, int OUT_BF>
__global__ __launch_bounds__(256) void mgemm_kernel(const unsigned short* __restrict__ A,
                                                    const unsigned short* __restrict__ WT,
                                                    const float* __restrict__ bias,
                                                    const int* __restrict__ deg_out,
                                                    float* __restrict__ outf,
                                                    unsigned short* __restrict__ outb, int N) {
  __shared__ unsigned short sWT[128 * 136];
  int tid = threadIdx.x;
  for (int g = tid; g < 2048; g += 256) {
    int n = g >> 4, c = g & 15;
    uint4 v = ((const uint4*)WT)[g];
    *(uint4*)&sWT[n * 136 + c * 8] = v;
  }
  int wv = tid >> 6;
  int lane = tid & 63;
  int q = lane >> 4;
  int ln = lane & 15;
  int row0 = blockIdx.x * 64 + wv * 16;
  int arow = row0 + ln;
  if (arow >= N) arow = 0;  // clamp; stores are guarded
  const unsigned short* Ar = A + (size_t)arow * 128 + q * 8;
  bf16x8 af0 = *(const bf16x8*)(Ar + 0);
  bf16x8 af1 = *(const bf16x8*)(Ar + 32);
  bf16x8 af2 = *(const bf16x8*)(Ar + 64);
  bf16x8 af3 = *(const bf16x8*)(Ar + 96);
  f32x4 acc[8];
#pragma unroll
  for (int t = 0; t < 8; ++t) acc[t] = (f32x4){0.f, 0.f, 0.f, 0.f};
  __syncthreads();
#pragma unroll
  for (int t = 0; t < 8; ++t) {
    const unsigned short* Wr = &sWT[(t * 16 + ln) * 136 + q * 8];
    bf16x8 b0 = *(const bf16x8*)(Wr + 0);
    bf16x8 b1 = *(const bf16x8*)(Wr + 32);
    bf16x8 b2 = *(const bf16x8*)(Wr + 64);
    bf16x8 b3 = *(const bf16x8*)(Wr + 96);
    acc[t] = __builtin_amdgcn_mfma_f32_16x16x32_bf16(af0, b0, acc[t], 0, 0, 0);
    acc[t] = __builtin_amdgcn_mfma_f32_16x16x32_bf16(af1, b1, acc[t], 0, 0, 0);
    acc[t] = __builtin_amdgcn_mfma_f32_16x16x32_bf16(af2, b2, acc[t], 0, 0, 0);
    acc[t] = __builtin_amdgcn_mfma_f32_16x16x32_bf16(af3, b3, acc[t], 0, 0, 0);
  }
  float scl[4];
#pragma unroll
  for (int r = 0; r < 4; ++r) {
    scl[r] = 1.0f;
    if (MODE == 1) {
      int row = row0 + q * 4 + r;
      int rr = (row < N) ? row : 0;
      scl[r] = rsqrtf(fmaxf((float)deg_out[rr], 1.0f));
    }
  }
#pragma unroll
  for (int t = 0; t < 8; ++t) {
    float b = bias[t * 16 + ln];
#pragma unroll
    for (int r = 0; r < 4; ++r) {
      int row = row0 + q * 4 + r;
      if (row < N) {
        float v = (acc[t][r] + b) * scl[r];
        if (OUT_BF)
          outb[(size_t)row * 128 + t * 16 + ln] = (unsigned short)bf16rne(v);
        else
          outf[(size_t)row * 128 + t * 16 + ln] = v;
      }
    }
  }
}

// ---------------- launcher ----------------

extern "C" void kernel_launch(void* const* d_in, const int* in_sizes, int n_in,
                              void* d_out, int out_size, void* d_ws, size_t ws_size,
                              hipStream_t stream) {
  const float* x = (const float*)d_in[0];
  const float* W1 = (const float*)d_in[1];
  const float* b1 = (const float*)d_in[2];
  const float* W2 = (const float*)d_in[3];
  const float* b2 = (const float*)d_in[4];
  const float* W3 = (const float*)d_in[5];
  const float* b3 = (const float*)d_in[6];
  const int* src = (const int*)d_in[7];
  const int* dst = (const int*)d_in[8];
  float* out = (float*)d_out;

  const int N = NN;

  // workspace layout (~46 MB)
  unsigned short* hbf = (unsigned short*)d_ws;             // (NN+1)*D bf16
  unsigned short* aggB = hbf + (size_t)(NN + 1) * D;       // NN*D bf16
  unsigned short* WT1 = aggB + (size_t)NN * D;             // 128*128 bf16
  unsigned short* WT2 = WT1 + D * D;
  unsigned short* WT3 = WT2 + D * D;
  int* partial_dst = (int*)(WT3 + D * D);                  // CH*NN
  int* partial_src = partial_dst + (size_t)CH * NN;        // CH*NN
  int* degtmp = partial_src + (size_t)CH * NN;             // NN
  int* deg_out = degtmp + NN;                              // NN
  int* row_ptr = deg_out + NN;                             // NN+1 (alloc NN+4)
  int* partials = row_ptr + NN + 4;                        // 256
  int* csr_src = partials + 256;                           // CSRCAP

  const int scanBlocks = (N + 255) / 256;  // 196

  cvtw_hist_kernel<<<HIST_BLOCKS + CVT_BLOCKS + WT_BLOCKS + 1, 1024, 0, stream>>>(
      x, W1, W2, W3, hbf, WT1, WT2, WT3, src, dst, partial_dst, partial_src);
  degscan_kernel<<<scanBlocks, 256, 0, stream>>>(partial_dst, partial_src, degtmp,
                                                 deg_out, row_ptr, partials, N);
  scan2<<<1, 256, 0, stream>>>(partials, scanBlocks);
  fill_kernel<<<CH * RGH, 1024, 0, stream>>>(src, dst, row_ptr, partials, partial_dst,
                                             csr_src);

  int aggBlocks = (N + 15) / 16;  // 3125
  int gemmBlocks = (N + 63) / 64;

  // layer 1: sage(x)
  agg_kernel<0><<<aggBlocks, 256, 0, stream>>>(hbf, row_ptr, partials, csr_src, degtmp,
                                               aggB, N);
  mgemm_kernel<0, 1><<<gemmBlocks, 256, 0, stream>>>(aggB, WT1, b1, deg_out, nullptr, hbf, N);
  // layer 2: sage(h1); fold norm_out for layer 3 into epilogue
  agg_kernel<0><<<aggBlocks, 256, 0, stream>>>(hbf, row_ptr, partials, csr_src, degtmp,
                                               aggB, N);
  mgemm_kernel<1, 1><<<gemmBlocks, 256, 0, stream>>>(aggB, WT2, b2, deg_out, nullptr, hbf, N);
  // layer 3: gcn: (agg(h2*norm_out) * norm_in) @ W3 + b3
  agg_kernel<1><<<aggBlocks, 256, 0, stream>>>(hbf, row_ptr, partials, csr_src, degtmp,
                                               aggB, N);
  mgemm_kernel<0, 0><<<gemmBlocks, 256, 0, stream>>>(aggB, WT3, b3, deg_out, out, nullptr, N);
}